// Round 6
// baseline (2199.313 us; speedup 1.0000x reference)
//
#include <hip/hip_runtime.h>

#define HB 16
#define HN 4096
#define HS 1024
#define HK 32
#define HC 128
#define NCOL (HB*HS*HK)   // 524288

typedef _Float16 half8  __attribute__((ext_vector_type(8)));
typedef _Float16 half4v __attribute__((ext_vector_type(4)));
typedef float    f32x4  __attribute__((ext_vector_type(4)));
typedef float    f32x2  __attribute__((ext_vector_type(2)));
typedef unsigned long long u64;

// ---- workspace offsets (bytes) ----  total = 154,288,128 B (~147 MB)
#define WS_STATS   0u
#define WS_BN      4096u
#define WS_A1H     8192u       // half [128][160]
#define WS_A2H     49152u      // half [128][128]
#define WS_A3H     81920u      // half [256][128]
#define WS_XYZPP   147456u     // float4 [16][4096]
#define WS_GIDX    1196032u    // int [16][1024][32]
#define WS_FEATT   3293184u    // half [16][4096][128]
#define WS_Y1      20070400u   // half [524288][128]  (also knn keybuf before conv1; y2 in place)

// =====================================================================
// Head kernel (256 threads/block):
//   blocks 0..15      FPS (one per batch, 4 waves, 16 pts/thread, barrier-free)
//   blocks 16..1039   feature transpose
//   blocks 1040..1295 xyzpp table
//   blocks 1296..1567 weight repack
// =====================================================================
__global__ __launch_bounds__(256) void head_kernel(
    const float* __restrict__ xyz, const float* __restrict__ features,
    const float* __restrict__ w1, const float* __restrict__ w2, const float* __restrict__ w3,
    _Float16* __restrict__ a1h, _Float16* __restrict__ a2h, _Float16* __restrict__ a3h,
    _Float16* __restrict__ featt, float4* __restrict__ xyzpp, float* __restrict__ out)
{
#pragma clang fp contract(off)
  __shared__ union {
    float tbuf[64][65];                       // 16.6 KB transpose tile
    struct { unsigned A[8][4]; unsigned B[8][4]; } fps;  // slotA {khi,klo,cx,cy}, slotB {cz,tag,0,0}
  } lds;
  const int bid = blockIdx.x;
  const int t = threadIdx.x;

  if (bid < 16) {
    // ---------------- FPS: bit-exact vs numpy reference ----------------
    const int b = bid;
    const float* xb = xyz + (size_t)b*HN*3;
    f32x2 pX[8], pY[8], pZ[8], dm[8];
    #pragma unroll
    for (int h = 0; h < 8; ++h) {
      #pragma unroll
      for (int e = 0; e < 2; ++e) {
        int n = t*16 + h*2 + e;
        pX[h][e] = xb[n*3+0]; pY[h][e] = xb[n*3+1]; pZ[h][e] = xb[n*3+2];
      }
      dm[h] = f32x2{1e10f, 1e10f};
    }
    float cx = xb[0], cy = xb[1], cz = xb[2];
    if (t == 0) { out[(size_t)(b*HS)*3+0] = cx; out[(size_t)(b*HS)*3+1] = cy; out[(size_t)(b*HS)*3+2] = cz; }
    const int wv = t >> 6, l = t & 63;
    if (t < 64) ((unsigned*)&lds.fps)[t] = 0;   // zero slot tags
    __syncthreads();                            // ONLY barrier; loop is barrier-free

    for (int i = 1; i < HS; ++i) {
      // ---- packed distance update (IEEE-identical per lane, contract off) ----
      f32x2 vcx = {cx, cx}, vcy = {cy, cy}, vcz = {cz, cz};
      #pragma unroll
      for (int h = 0; h < 8; ++h) {
        f32x2 dx = pX[h] - vcx, dy = pY[h] - vcy, dz = pZ[h] - vcz;
        f32x2 d = ((dx*dx) + (dy*dy)) + (dz*dz);      // matches np sum order
        dm[h] = __builtin_elementwise_min(dm[h], d);
      }
      // ---- pk max tree ----
      f32x2 l1a = __builtin_elementwise_max(dm[0], dm[1]);
      f32x2 l1b = __builtin_elementwise_max(dm[2], dm[3]);
      f32x2 l1c = __builtin_elementwise_max(dm[4], dm[5]);
      f32x2 l1d = __builtin_elementwise_max(dm[6], dm[7]);
      f32x2 l2a = __builtin_elementwise_max(l1a, l1b);
      f32x2 l2b = __builtin_elementwise_max(l1c, l1d);
      f32x2 l3  = __builtin_elementwise_max(l2a, l2b);
      float val = fmaxf(l3[0], l3[1]);
      // ---- first (h,e) matching val; carry coords (reverse loop = first-index priority) ----
      int nkey = 0, eb = 0;
      f32x2 sX = pX[0], sY = pY[0], sZ = pZ[0];
      #pragma unroll
      for (int h = 7; h >= 0; --h) {
        bool m0 = (dm[h][0] == val);
        bool m1 = (dm[h][1] == val);
        int e = m0 ? 0 : 1;
        if (m0 | m1) { nkey = t*16 + 2*h + e; eb = e; sX = pX[h]; sY = pY[h]; sZ = pZ[h]; }
      }
      float sx = eb ? sX[1] : sX[0];
      float sy = eb ? sY[1] : sY[0];
      float sz = eb ? sZ[1] : sZ[0];
      // ---- wave tournament via DPP carrying {khi,klo,cx,cy,cz}; result lands in lane 63 ----
      int ikhi = (int)__float_as_uint(val);
      int iklo = (int)((((unsigned)i) << 12) | (unsigned)(4095 - nkey));  // tag | inv-index
      int scx = __float_as_int(sx), scy = __float_as_int(sy), scz = __float_as_int(sz);
      #define TSTEP(ctrl) { \
        int nh_ = __builtin_amdgcn_update_dpp(ikhi, ikhi, ctrl, 0xF, 0xF, false); \
        int nl_ = __builtin_amdgcn_update_dpp(iklo, iklo, ctrl, 0xF, 0xF, false); \
        int nx_ = __builtin_amdgcn_update_dpp(scx, scx, ctrl, 0xF, 0xF, false); \
        int ny_ = __builtin_amdgcn_update_dpp(scy, scy, ctrl, 0xF, 0xF, false); \
        int nz_ = __builtin_amdgcn_update_dpp(scz, scz, ctrl, 0xF, 0xF, false); \
        bool g_ = ((unsigned)nh_ > (unsigned)ikhi) || ((nh_ == ikhi) && ((unsigned)nl_ > (unsigned)iklo)); \
        ikhi = g_ ? nh_ : ikhi; iklo = g_ ? nl_ : iklo; \
        scx = g_ ? nx_ : scx; scy = g_ ? ny_ : scy; scz = g_ ? nz_ : scz; }
      TSTEP(0x111) TSTEP(0x112) TSTEP(0x114) TSTEP(0x118) TSTEP(0x142) TSTEP(0x143)
      #undef TSTEP
      const int p4 = (i & 1) * 4;
      if (l == 63) {
        *(uint4*)&lds.fps.A[p4 + wv][0] = uint4{(unsigned)ikhi, (unsigned)iklo, (unsigned)scx, (unsigned)scy};
        *(uint4*)&lds.fps.B[p4 + wv][0] = uint4{(unsigned)scz, (unsigned)i, 0u, 0u};
      }
      // ---- lock-free poll: tags first, data after (volatile keeps order) ----
      volatile u64* pa = (volatile u64*)&lds.fps.A[p4][0];  // [2w]={khi,klo} [2w+1]={cx,cy}
      volatile u64* pb = (volatile u64*)&lds.fps.B[p4][0];  // [2w]={cz,tag}
      u64 a0,a1,a2,a3,b0,b1,b2,b3,c0,c1,c2,c3;
      const unsigned tg = (unsigned)i;
      for (;;) {
        a0 = pa[0]; a1 = pa[2]; a2 = pa[4]; a3 = pa[6];
        b0 = pb[0]; b1 = pb[2]; b2 = pb[4]; b3 = pb[6];
        c0 = pa[1]; c1 = pa[3]; c2 = pa[5]; c3 = pa[7];
        bool ok = ((unsigned)(a0 >> 44) == tg) & ((unsigned)(a1 >> 44) == tg) &
                  ((unsigned)(a2 >> 44) == tg) & ((unsigned)(a3 >> 44) == tg) &
                  ((unsigned)(b0 >> 32) == tg) & ((unsigned)(b1 >> 32) == tg) &
                  ((unsigned)(b2 >> 32) == tg) & ((unsigned)(b3 >> 32) == tg);
        if (ok) break;
      }
      // ---- pick global winner among 4 bundles (khi major, klo minor) ----
      u64 k0 = (a0 << 32) | (a0 >> 32);   // {khi:klo} as one comparable u64
      u64 k1 = (a1 << 32) | (a1 >> 32);
      u64 k2 = (a2 << 32) | (a2 >> 32);
      u64 k3 = (a3 << 32) | (a3 >> 32);
      u64 kA = k0; u64 cA = c0; u64 zA = b0;
      if (k1 > kA) { kA = k1; cA = c1; zA = b1; }
      u64 kB = k2; u64 cB = c2; u64 zB = b2;
      if (k3 > kB) { kB = k3; cB = c3; zB = b3; }
      if (kB > kA) { kA = kB; cA = cB; zA = zB; }
      cx = __uint_as_float((unsigned)cA);
      cy = __uint_as_float((unsigned)(cA >> 32));
      cz = __uint_as_float((unsigned)zA);
      if (t == 0) {                        // store flies free (no barrier ever drains it)
        size_t o3 = (size_t)(b*HS + i)*3;
        out[o3+0] = cx; out[o3+1] = cy; out[o3+2] = cz;
      }
    }
  } else if (bid < 16 + 1024) {
    // -------- feature transpose [B,C,N]f32 -> [B,N,C]fp16, 2 channel-halves --------
    const int tb = bid - 16;
    const int bb = tb >> 6, n0 = (tb & 63) * 64;
    const int wvv = t >> 6, lane = t & 63;       // 4 waves
    for (int h = 0; h < 2; ++h) {
      #pragma unroll
      for (int rep = 0; rep < 16; ++rep) {
        int cc = rep*4 + wvv;
        lds.tbuf[cc][lane] = features[((size_t)(bb*HC + h*64 + cc))*HN + n0 + lane];
      }
      __syncthreads();
      #pragma unroll
      for (int rep = 0; rep < 2; ++rep) {
        int item = rep*256 + t;
        int n = item >> 3, cg = (item & 7) * 8;
        half8 v;
        #pragma unroll
        for (int j = 0; j < 8; ++j) v[j] = (_Float16)lds.tbuf[cg + j][n];
        *(half8*)(featt + ((size_t)(bb*HN) + n0 + n) * HC + h*64 + cg) = v;
      }
      __syncthreads();
    }
  } else if (bid < 16 + 1024 + 256) {
    // ---------------- xyzpp table ----------------
    int gi = (bid - 1040)*256 + t;
    const float* p = xyz + (size_t)gi*3;
    float x = p[0], y = p[1], z = p[2];
    float pp = ((x*x) + (y*y)) + (z*z);
    xyzpp[gi] = make_float4(x, y, z, pp);
  } else {
    // ---------------- weight repack to fp16 ----------------
    int wi = (bid - 1296)*256 + t;
    if (wi < 20480) {
      int o = wi / 160, c = wi - o*160;
      float v = 0.0f;
      if (c < 128) v = w1[o*131 + 3 + c];        // feature part
      else if (c < 131) v = w1[o*131 + (c-128)]; // gxn part
      a1h[wi] = (_Float16)v;
    } else if (wi < 20480 + 16384) {
      a2h[wi - 20480] = (_Float16)w2[wi - 20480];
    } else if (wi < 20480 + 16384 + 32768) {
      a3h[wi - 36864] = (_Float16)w3[wi - 36864];
    }
  }
}

// =====================================================================
// KNN phase 1: 8 shards/batch; per-thread FIFO + bitonic flush over 512 pts
// outputs per-shard sorted top-32 as sortable u64 keys (d-bits|idx)
// =====================================================================
#define LEXLT(d1,i1,d2,i2) ((d1) < (d2) || ((d1) == (d2) && (i1) < (i2)))

__global__ __launch_bounds__(64) void knn_p1(
    const float* __restrict__ newxyz, const float4* __restrict__ xyzpp, u64* __restrict__ keybuf)
{
#pragma clang fp contract(off)
  const int t = threadIdx.x;
  const int blk = blockIdx.x;
  const int b = blk >> 7, rem = blk & 127;
  const int shard = rem >> 4, qg = rem & 15;
  const int q = b*1024 + qg*64 + t;
  float qx = newxyz[(size_t)q*3+0], qy = newxyz[(size_t)q*3+1], qz = newxyz[(size_t)q*3+2];
  float qq = ((qx*qx) + (qy*qy)) + (qz*qz);

  const float INF = __builtin_inff();
  float td[32]; int ti[32];
  #pragma unroll
  for (int j = 0; j < 32; ++j) { td[j] = INF; ti[j] = 0x7FFFFFFF; }
  float root = INF;
  int cnt = 0;

  __shared__ float fdl[32][64];
  __shared__ int   fil[32][64];
  const float4* P = xyzpp + (size_t)b*HN + shard*512;

  auto flush = [&]() {
    float gd[32]; int gi2[32];
    #pragma unroll
    for (int j = 0; j < 32; ++j) {
      gd[j] = fdl[j][t]; gi2[j] = fil[j][t];
      if (j >= cnt) { gd[j] = INF; gi2[j] = 0x7FFFFFFF; }
    }
    cnt = 0;
    #pragma unroll
    for (int k = 2; k <= 32; k <<= 1) {
      #pragma unroll
      for (int j = k >> 1; j > 0; j >>= 1) {
        #pragma unroll
        for (int i = 0; i < 32; ++i) {
          int l = i ^ j;
          if (l > i) {
            bool up = ((i & k) == 0);
            bool sw = up ? LEXLT(gd[l], gi2[l], gd[i], gi2[i])
                         : LEXLT(gd[i], gi2[i], gd[l], gi2[l]);
            if (sw) { float tf = gd[i]; gd[i] = gd[l]; gd[l] = tf;
                      int   ii = gi2[i]; gi2[i] = gi2[l]; gi2[l] = ii; }
          }
        }
      }
    }
    #pragma unroll
    for (int i = 0; i < 32; ++i) {
      float od = gd[31-i]; int oi = gi2[31-i];
      if (LEXLT(od, oi, td[i], ti[i])) { td[i] = od; ti[i] = oi; }
    }
    #pragma unroll
    for (int j = 16; j > 0; j >>= 1) {
      #pragma unroll
      for (int i = 0; i < 32; ++i) {
        if ((i & j) == 0) {
          int l = i | j;
          if (LEXLT(td[l], ti[l], td[i], ti[i])) {
            float tf = td[i]; td[i] = td[l]; td[l] = tf;
            int   ii = ti[i]; ti[i] = ti[l]; ti[l] = ii;
          }
        }
      }
    }
    root = td[31];
  };

  for (int n0 = 0; n0 < 512; n0 += 8) {
    float4 pb[8];
    #pragma unroll
    for (int j = 0; j < 8; ++j) pb[j] = P[n0 + j];
    #pragma unroll
    for (int j = 0; j < 8; ++j) {
      float d = (qq + pb[j].w) - 2.0f*(((qx*pb[j].x) + (qy*pb[j].y)) + (qz*pb[j].z));
      if (d < root) { fdl[cnt][t] = d; fil[cnt][t] = shard*512 + n0 + j; cnt++; }
    }
    if (__ballot(cnt > 24)) flush();
  }
  if (__ballot(cnt > 0)) flush();

  // sortable u64 keys: (order-preserving f32 map << 32) | idx
  const size_t base = (size_t)(b*16 + qg) * 16384 + (size_t)shard * 2048;
  #pragma unroll
  for (int j = 0; j < 32; ++j) {
    unsigned bits = __float_as_uint(td[j]);
    unsigned s = bits ^ (((unsigned)((int)bits >> 31)) | 0x80000000u);
    keybuf[base + (size_t)j*64 + t] = ((u64)s << 32) | (unsigned)ti[j];
  }
}

// =====================================================================
// KNN phase 2: merge 8 shard-lists (8x32 keys) per query -> top-32 indices
// =====================================================================
__global__ __launch_bounds__(64) void knn_p2(const u64* __restrict__ keybuf, int* __restrict__ gidx)
{
  const int t = threadIdx.x;
  const int g = blockIdx.x;                 // (b*16 + qg)
  const size_t base = (size_t)g * 16384;

  u64 tk[32];
  #pragma unroll
  for (int j = 0; j < 32; ++j) tk[j] = ~0ULL;
  u64 root = ~0ULL;
  int cnt = 0;
  __shared__ u64 fk[32][64];

  auto flush64 = [&]() {
    u64 gd[32];
    #pragma unroll
    for (int j = 0; j < 32; ++j) {
      gd[j] = fk[j][t];
      if (j >= cnt) gd[j] = ~0ULL;
    }
    cnt = 0;
    #pragma unroll
    for (int k = 2; k <= 32; k <<= 1) {
      #pragma unroll
      for (int j = k >> 1; j > 0; j >>= 1) {
        #pragma unroll
        for (int i = 0; i < 32; ++i) {
          int l = i ^ j;
          if (l > i) {
            bool up = ((i & k) == 0);
            bool sw = up ? (gd[l] < gd[i]) : (gd[i] < gd[l]);
            if (sw) { u64 tf = gd[i]; gd[i] = gd[l]; gd[l] = tf; }
          }
        }
      }
    }
    #pragma unroll
    for (int i = 0; i < 32; ++i) {
      u64 od = gd[31-i];
      if (od < tk[i]) tk[i] = od;
    }
    #pragma unroll
    for (int j = 16; j > 0; j >>= 1) {
      #pragma unroll
      for (int i = 0; i < 32; ++i) {
        if ((i & j) == 0) {
          int l = i | j;
          if (tk[l] < tk[i]) { u64 tf = tk[i]; tk[i] = tk[l]; tk[l] = tf; }
        }
      }
    }
    root = tk[31];
  };

  for (int k0 = 0; k0 < 256; k0 += 8) {
    u64 kk[8];
    #pragma unroll
    for (int j = 0; j < 8; ++j) kk[j] = keybuf[base + (size_t)(k0 + j)*64 + t];
    #pragma unroll
    for (int j = 0; j < 8; ++j) {
      if (kk[j] < root) { fk[cnt][t] = kk[j]; cnt++; }
    }
    if (__ballot(cnt > 24)) flush64();
  }
  if (__ballot(cnt > 0)) flush64();

  const int q = g*64 + t;
  #pragma unroll
  for (int j = 0; j < 32; j += 4) {
    int4 v = { (int)(unsigned)tk[j], (int)(unsigned)tk[j+1], (int)(unsigned)tk[j+2], (int)(unsigned)tk[j+3] };
    *(int4*)(gidx + ((size_t)q << 5) + j) = v;
  }
}

// =====================================================================
// Fused conv+BN(+relu)+stats (+pool for MODE 3), fp16 MFMA 16x16x32
// =====================================================================
template<int MODE>
__global__ __launch_bounds__(256, 2) void conv_kernel(
    const _Float16* __restrict__ A, const _Float16* Bsrc,
    const int* __restrict__ gidx, const float4* __restrict__ xyzpp, const float* __restrict__ newxyz,
    const _Float16* __restrict__ bnA, const _Float16* __restrict__ bnB,
    _Float16* Yout, float* __restrict__ osum, float* __restrict__ osq,
    float* __restrict__ pool)
{
  const int tid = threadIdx.x;
  const int w = tid >> 6, l = tid & 63, ll = l & 15, lh = l >> 4;
  const int colbase = blockIdx.x * 256 + w * 64;
  const int b = colbase >> 15;
  const int AS = (MODE == 1) ? 160 : 128;
  const _Float16* Ap = A + (MODE == 3 ? (size_t)blockIdx.y * 128 * 128 : 0);

  f32x4 acc[8][4] = {};

  half8 bnAv[4], bnBv[4];
  if constexpr (MODE >= 2) {
    #pragma unroll
    for (int c = 0; c < 4; ++c) {
      int k0 = c*32 + lh*8;
      bnAv[c] = *(const half8*)(bnA + k0);
      bnBv[c] = *(const half8*)(bnB + k0);
    }
  }
  int gidxv[4];
  if constexpr (MODE == 1) {
    #pragma unroll
    for (int nf = 0; nf < 4; ++nf) gidxv[nf] = gidx[colbase + nf*16 + ll];
  }

  const int NCH = (MODE == 1) ? 5 : 4;
  #pragma unroll
  for (int c = 0; c < NCH; ++c) {
    half8 a[8];
    #pragma unroll
    for (int mf = 0; mf < 8; ++mf)
      a[mf] = *(const half8*)(Ap + (size_t)(mf*16 + ll)*AS + c*32 + lh*8);
    half8 bfr[4];
    #pragma unroll
    for (int nf = 0; nf < 4; ++nf) {
      if constexpr (MODE == 1) {
        if (c < 4) {
          bfr[nf] = *(const half8*)(Bsrc + ((size_t)(b*HN + gidxv[nf]))*HC + c*32 + lh*8);
        } else {
          half8 z = {};
          if (lh == 0) {
            float4 pw = xyzpp[b*HN + gidxv[nf]];
            int col = colbase + nf*16 + ll;
            int s = (col >> 5) & (HS-1);
            const float* nx = newxyz + (size_t)(b*HS + s)*3;
            z[0] = (_Float16)(pw.x - nx[0]);
            z[1] = (_Float16)(pw.y - nx[1]);
            z[2] = (_Float16)(pw.z - nx[2]);
          }
          bfr[nf] = z;
        }
      } else {
        half8 v = *(const half8*)(Bsrc + ((size_t)(colbase + nf*16 + ll))*HC + c*32 + lh*8);
        v = v * bnAv[c] + bnBv[c];
        half8 hz = {};
        bfr[nf] = __builtin_elementwise_max(v, hz);
      }
    }
    #pragma unroll
    for (int mf = 0; mf < 8; ++mf)
      #pragma unroll
      for (int nf = 0; nf < 4; ++nf)
        acc[mf][nf] = __builtin_amdgcn_mfma_f32_16x16x32_f16(a[mf], bfr[nf], acc[mf][nf], 0, 0, 0);
  }

  // ---------------- epilogue ----------------
  __shared__ float bsum[128], bsq[128];
  if (tid < 128) { bsum[tid] = 0.0f; bsq[tid] = 0.0f; }
  __syncthreads();

  #pragma unroll
  for (int mf = 0; mf < 8; ++mf) {
    int ch0 = mf*16 + lh*4;
    if constexpr (MODE != 3) {
      #pragma unroll
      for (int nf = 0; nf < 4; ++nf) {
        int col = colbase + nf*16 + ll;
        half4v hv;
        #pragma unroll
        for (int r = 0; r < 4; ++r) hv[r] = (_Float16)acc[mf][nf][r];
        *(half4v*)(Yout + (size_t)col*HC + ch0) = hv;
      }
    } else {
      #pragma unroll
      for (int g = 0; g < 2; ++g) {
        float mx[4];
        #pragma unroll
        for (int r = 0; r < 4; ++r) mx[r] = fmaxf(acc[mf][2*g][r], acc[mf][2*g+1][r]);
        #pragma unroll
        for (int m = 1; m <= 8; m <<= 1)
          #pragma unroll
          for (int r = 0; r < 4; ++r) mx[r] = fmaxf(mx[r], __shfl_xor(mx[r], m, 64));
        if (ll == 0) {
          int s = ((colbase + g*32) >> 5) & (HS-1);
          int chg = blockIdx.y*128 + ch0;
          #pragma unroll
          for (int r = 0; r < 4; ++r)
            pool[(((size_t)(b*256 + chg + r)) << 10) + s] = mx[r];
        }
      }
    }
    float sv[4] = {0,0,0,0}, qv[4] = {0,0,0,0};
    #pragma unroll
    for (int nf = 0; nf < 4; ++nf)
      #pragma unroll
      for (int r = 0; r < 4; ++r) { float v = acc[mf][nf][r]; sv[r] += v; qv[r] += v*v; }
    #pragma unroll
    for (int m = 1; m <= 8; m <<= 1)
      #pragma unroll
      for (int r = 0; r < 4; ++r) { sv[r] += __shfl_xor(sv[r], m, 64); qv[r] += __shfl_xor(qv[r], m, 64); }
    if (ll == 0) {
      #pragma unroll
      for (int r = 0; r < 4; ++r) { atomicAdd(&bsum[ch0+r], sv[r]); atomicAdd(&bsq[ch0+r], qv[r]); }
    }
  }
  __syncthreads();
  if (tid < 128) {
    int choff = (MODE == 3) ? blockIdx.y*128 : 0;
    atomicAdd(&osum[choff + tid], bsum[tid]);
    atomicAdd(&osq[choff + tid], bsq[tid]);
  }
}

// =====================================================================
__global__ void fin_kernel(const float* __restrict__ sum, const float* __restrict__ sq,
                           const float* __restrict__ g, const float* __restrict__ be,
                           _Float16* __restrict__ Ah, _Float16* __restrict__ Bh,
                           float* __restrict__ Af, float* __restrict__ Bf, int C)
{
  int c = threadIdx.x;
  if (c < C) {
    float mean = sum[c] * (1.0f/524288.0f);
    float var  = sq[c]  * (1.0f/524288.0f) - mean*mean;
    float a  = g[c] * rsqrtf(var + 1e-5f);
    float bb = be[c] - mean*a;
    if (Ah) { Ah[c] = (_Float16)a; Bh[c] = (_Float16)bb; }
    else    { Af[c] = a; Bf[c] = bb; }
  }
}

// =====================================================================
__global__ __launch_bounds__(256) void final_affine(float* __restrict__ outp,
                                                    const float* __restrict__ Af,
                                                    const float* __restrict__ Bf)
{
  int i = blockIdx.x*256 + threadIdx.x;
  float4 v = ((float4*)outp)[i];
  int ch = ((i << 2) >> 10) & 255;
  float a = Af[ch], bb = Bf[ch];
  v.x = fmaxf(v.x*a + bb, 0.0f);
  v.y = fmaxf(v.y*a + bb, 0.0f);
  v.z = fmaxf(v.z*a + bb, 0.0f);
  v.w = fmaxf(v.w*a + bb, 0.0f);
  ((float4*)outp)[i] = v;
}

// =====================================================================
extern "C" void kernel_launch(void* const* d_in, const int* in_sizes, int n_in,
                              void* d_out, int out_size, void* d_ws, size_t ws_size,
                              hipStream_t stream) {
  const float* xyz      = (const float*)d_in[0];
  const float* features = (const float*)d_in[1];
  const float* w1  = (const float*)d_in[2];
  const float* g1  = (const float*)d_in[3];
  const float* b1v = (const float*)d_in[4];
  const float* w2  = (const float*)d_in[5];
  const float* g2  = (const float*)d_in[6];
  const float* b2v = (const float*)d_in[7];
  const float* w3  = (const float*)d_in[8];
  const float* g3  = (const float*)d_in[9];
  const float* b3v = (const float*)d_in[10];
  float* out = (float*)d_out;
  char* ws = (char*)d_ws;

  float* stats = (float*)(ws + WS_STATS);
  float* sum1 = stats;       float* sq1 = stats + 128;
  float* sum2 = stats + 256; float* sq2 = stats + 384;
  float* sum3 = stats + 512; float* sq3 = stats + 768;
  _Float16* A1h = (_Float16*)(ws + WS_BN);
  _Float16* B1h = A1h + 128;
  _Float16* A2h = A1h + 256;
  _Float16* B2h = A1h + 384;
  float* a3f = (float*)(ws + WS_BN + 1024);
  float* b3f = a3f + 256;
  _Float16* a1h = (_Float16*)(ws + WS_A1H);
  _Float16* a2h = (_Float16*)(ws + WS_A2H);
  _Float16* a3h = (_Float16*)(ws + WS_A3H);
  float4* xyzpp = (float4*)(ws + WS_XYZPP);
  int* gidx = (int*)(ws + WS_GIDX);
  _Float16* featt = (_Float16*)(ws + WS_FEATT);
  u64* keybuf = (u64*)(ws + WS_Y1);       // y1 region reused before conv1
  _Float16* y1 = (_Float16*)(ws + WS_Y1);
  _Float16* y2 = y1;   // conv2 output overwrites y1 in place (per-column independence)

  hipMemsetAsync(ws + WS_STATS, 0, 4096, stream);

  head_kernel<<<1568, 256, 0, stream>>>(xyz, features, w1, w2, w3,
                                        a1h, a2h, a3h, featt, xyzpp, out);
  knn_p1<<<2048, 64, 0, stream>>>(out, xyzpp, keybuf);
  knn_p2<<<256, 64, 0, stream>>>(keybuf, gidx);

  conv_kernel<1><<<2048, 256, 0, stream>>>(a1h, featt, gidx, xyzpp, out,
                                           nullptr, nullptr, y1, sum1, sq1, nullptr);
  fin_kernel<<<1, 256, 0, stream>>>(sum1, sq1, g1, b1v, A1h, B1h, nullptr, nullptr, 128);

  conv_kernel<2><<<2048, 256, 0, stream>>>(a2h, y1, nullptr, nullptr, nullptr,
                                           A1h, B1h, y2, sum2, sq2, nullptr);
  fin_kernel<<<1, 256, 0, stream>>>(sum2, sq2, g2, b2v, A2h, B2h, nullptr, nullptr, 128);

  conv_kernel<3><<<dim3(2048, 2), 256, 0, stream>>>(a3h, y2, nullptr, nullptr, nullptr,
                                                    A2h, B2h, nullptr, sum3, sq3, out + 49152);
  fin_kernel<<<1, 256, 0, stream>>>(sum3, sq3, g3, b3v, nullptr, nullptr, a3f, b3f, 256);

  final_affine<<<4096, 256, 0, stream>>>(out + 49152, a3f, b3f);
}

// Round 7
// 1635.441 us; speedup vs baseline: 1.3448x; 1.3448x over previous
//
#include <hip/hip_runtime.h>

#define HB 16
#define HN 4096
#define HS 1024
#define HK 32
#define HC 128
#define NCOL (HB*HS*HK)   // 524288

typedef _Float16 half8  __attribute__((ext_vector_type(8)));
typedef _Float16 half4v __attribute__((ext_vector_type(4)));
typedef float    f32x4  __attribute__((ext_vector_type(4)));
typedef float    f32x2  __attribute__((ext_vector_type(2)));
typedef unsigned long long u64;

// ---- workspace offsets (bytes) ----  total = 154,288,128 B (~147 MB)
#define WS_STATS   0u
#define WS_BN      4096u
#define WS_A1H     8192u       // half [128][160]
#define WS_A2H     49152u      // half [128][128]
#define WS_A3H     81920u      // half [256][128]
#define WS_XYZPP   147456u     // float4 [16][4096]
#define WS_GIDX    1196032u    // int [16][1024][32]
#define WS_FEATT   3293184u    // half [16][4096][128]
#define WS_Y1      20070400u   // half [524288][128]  (also knn keybuf before conv1; y2 in place)

// =====================================================================
// Head kernel (256 threads/block):
//   blocks 0..15      FPS (one per batch, 4 waves, 16 pts/thread)
//   blocks 16..1039   feature transpose
//   blocks 1040..1295 xyzpp table
//   blocks 1296..1567 weight repack
// =====================================================================
__global__ __launch_bounds__(256) void head_kernel(
    const float* __restrict__ xyz, const float* __restrict__ features,
    const float* __restrict__ w1, const float* __restrict__ w2, const float* __restrict__ w3,
    _Float16* __restrict__ a1h, _Float16* __restrict__ a2h, _Float16* __restrict__ a3h,
    _Float16* __restrict__ featt, float4* __restrict__ xyzpp, float* __restrict__ out)
{
#pragma clang fp contract(off)
  __shared__ union {
    float tbuf[64][65];                       // 16.6 KB transpose tile
    struct { uint4 A[2][4]; unsigned Z[2][4]; } fps;  // slot {khi,klo,cx,cy} + z-word, dbuf
  } lds;
  const int bid = blockIdx.x;
  const int t = threadIdx.x;

  if (bid < 16) {
    // ---------------- FPS: bit-exact vs numpy reference ----------------
    const int b = bid;
    const float* xb = xyz + (size_t)b*HN*3;
    f32x2 pX[8], pY[8], pZ[8], dm[8];
    #pragma unroll
    for (int h = 0; h < 8; ++h) {
      #pragma unroll
      for (int e = 0; e < 2; ++e) {
        int n = t*16 + h*2 + e;
        pX[h][e] = xb[n*3+0]; pY[h][e] = xb[n*3+1]; pZ[h][e] = xb[n*3+2];
      }
      dm[h] = f32x2{1e10f, 1e10f};
    }
    float cx = xb[0], cy = xb[1], cz = xb[2];
    float sc[4][3];
    #pragma unroll
    for (int k = 0; k < 4; ++k) { sc[k][0]=0.0f; sc[k][1]=0.0f; sc[k][2]=0.0f; }
    if (t == 0) { out[(size_t)(b*HS)*3+0] = cx; out[(size_t)(b*HS)*3+1] = cy; out[(size_t)(b*HS)*3+2] = cz; }
    const int wv = t >> 6, l = t & 63;

    for (int i = 1; i < HS; ++i) {
      // ---- packed distance update (IEEE-identical per lane, contract off) ----
      f32x2 vcx = {cx, cx}, vcy = {cy, cy}, vcz = {cz, cz};
      float pm[8];
      #pragma unroll
      for (int h = 0; h < 8; ++h) {
        f32x2 dx = pX[h] - vcx, dy = pY[h] - vcy, dz = pZ[h] - vcz;
        f32x2 d = ((dx*dx) + (dy*dy)) + (dz*dz);      // matches np sum order
        f32x2 nd = __builtin_elementwise_min(dm[h], d);
        dm[h] = nd;
        pm[h] = fmaxf(nd[0], nd[1]);
      }
      // ---- thread max via fmax tree ----
      float q0 = fmaxf(pm[0], pm[1]), q1 = fmaxf(pm[2], pm[3]);
      float q2 = fmaxf(pm[4], pm[5]), q3 = fmaxf(pm[6], pm[7]);
      float val = fmaxf(fmaxf(q0, q1), fmaxf(q2, q3));
      // ---- first (h,e) matching val; keep that candidate's coords ----
      int nkey = 0;
      float bx = pX[0][0], by = pY[0][0], bz = pZ[0][0];
      #pragma unroll
      for (int h = 7; h >= 0; --h) {
        bool m0 = (dm[h][0] == val);
        bool m1 = (dm[h][1] == val);
        if (m0 | m1) {
          int e = m0 ? 0 : 1;
          nkey = t*16 + 2*h + e;
          bx = m0 ? pX[h][0] : pX[h][1];
          by = m0 ? pY[h][0] : pY[h][1];
          bz = m0 ? pZ[h][0] : pZ[h][1];
        }
      }
      // ---- wave tournament via DPP on {khi,klo}; lane 63 holds wave winner ----
      int ikhi = (int)__float_as_uint(val);
      int iklo = HN-1 - nkey;                  // bigger = smaller index
      #define TSTEP(ctrl) { \
        int nh_ = __builtin_amdgcn_update_dpp(ikhi, ikhi, ctrl, 0xF, 0xF, false); \
        int nl_ = __builtin_amdgcn_update_dpp(iklo, iklo, ctrl, 0xF, 0xF, false); \
        bool g_ = ((unsigned)nh_ > (unsigned)ikhi) || ((nh_ == ikhi) && (nl_ > iklo)); \
        ikhi = g_ ? nh_ : ikhi; iklo = g_ ? nl_ : iklo; }
      TSTEP(0x111) TSTEP(0x112) TSTEP(0x114) TSTEP(0x118) TSTEP(0x142) TSTEP(0x143)
      #undef TSTEP
      unsigned wkhi = (unsigned)__builtin_amdgcn_readlane(ikhi, 63);
      int wklo = __builtin_amdgcn_readlane(iklo, 63);
      int n_w = HN-1 - wklo;                   // wave-winner point index
      int wlane = n_w >> 4;                    // owning lane
      float wx = __int_as_float(__builtin_amdgcn_readlane(__float_as_int(bx), wlane));
      float wy = __int_as_float(__builtin_amdgcn_readlane(__float_as_int(by), wlane));
      float wz = __int_as_float(__builtin_amdgcn_readlane(__float_as_int(bz), wlane));

      const int p = i & 1;
      if (l == 0) {
        lds.fps.A[p][wv] = uint4{wkhi, (unsigned)wklo, __float_as_uint(wx), __float_as_uint(wy)};
        lds.fps.Z[p][wv] = __float_as_uint(wz);
      }
      __syncthreads();                          // single barrier per iter (dbuf)
      uint4 A0 = lds.fps.A[p][0];
      uint4 A1 = lds.fps.A[p][1];
      uint4 A2 = lds.fps.A[p][2];
      uint4 A3 = lds.fps.A[p][3];
      uint4 Zv = *(const uint4*)&lds.fps.Z[p][0];
      u64 k0 = ((u64)A0.x << 32) | A0.y;
      u64 k1 = ((u64)A1.x << 32) | A1.y;
      u64 k2 = ((u64)A2.x << 32) | A2.y;
      u64 k3 = ((u64)A3.x << 32) | A3.y;
      u64 kA = k0; unsigned xA = A0.z, yA = A0.w, zA = Zv.x;
      if (k1 > kA) { kA = k1; xA = A1.z; yA = A1.w; zA = Zv.y; }
      u64 kB = k2; unsigned xB = A2.z, yB = A2.w, zB = Zv.z;
      if (k3 > kB) { kB = k3; xB = A3.z; yB = A3.w; zB = Zv.w; }
      if (kB > kA) { kA = kB; xA = xB; yA = yB; zA = zB; }
      cx = __uint_as_float(xA); cy = __uint_as_float(yA); cz = __uint_as_float(zA);
      if ((i & 255) == t) {                     // defer stores to registers
        int s = i >> 8;
        #pragma unroll
        for (int k = 0; k < 4; ++k)
          if (s == k) { sc[k][0] = cx; sc[k][1] = cy; sc[k][2] = cz; }
      }
    }
    // ---- post-loop: coalesced new_xyz stores ----
    #pragma unroll
    for (int k = 0; k < 4; ++k) {
      int i = k*256 + t;
      if (i >= 1) {
        size_t o3 = (size_t)(b*HS + i)*3;
        out[o3+0] = sc[k][0]; out[o3+1] = sc[k][1]; out[o3+2] = sc[k][2];
      }
    }
  } else if (bid < 16 + 1024) {
    // -------- feature transpose [B,C,N]f32 -> [B,N,C]fp16, 2 channel-halves --------
    const int tb = bid - 16;
    const int bb = tb >> 6, n0 = (tb & 63) * 64;
    const int wvv = t >> 6, lane = t & 63;       // 4 waves
    for (int h = 0; h < 2; ++h) {
      #pragma unroll
      for (int rep = 0; rep < 16; ++rep) {
        int cc = rep*4 + wvv;
        lds.tbuf[cc][lane] = features[((size_t)(bb*HC + h*64 + cc))*HN + n0 + lane];
      }
      __syncthreads();
      #pragma unroll
      for (int rep = 0; rep < 2; ++rep) {
        int item = rep*256 + t;
        int n = item >> 3, cg = (item & 7) * 8;
        half8 v;
        #pragma unroll
        for (int j = 0; j < 8; ++j) v[j] = (_Float16)lds.tbuf[cg + j][n];
        *(half8*)(featt + ((size_t)(bb*HN) + n0 + n) * HC + h*64 + cg) = v;
      }
      __syncthreads();
    }
  } else if (bid < 16 + 1024 + 256) {
    // ---------------- xyzpp table ----------------
    int gi = (bid - 1040)*256 + t;
    const float* p = xyz + (size_t)gi*3;
    float x = p[0], y = p[1], z = p[2];
    float pp = ((x*x) + (y*y)) + (z*z);
    xyzpp[gi] = make_float4(x, y, z, pp);
  } else {
    // ---------------- weight repack to fp16 ----------------
    int wi = (bid - 1296)*256 + t;
    if (wi < 20480) {
      int o = wi / 160, c = wi - o*160;
      float v = 0.0f;
      if (c < 128) v = w1[o*131 + 3 + c];        // feature part
      else if (c < 131) v = w1[o*131 + (c-128)]; // gxn part
      a1h[wi] = (_Float16)v;
    } else if (wi < 20480 + 16384) {
      a2h[wi - 20480] = (_Float16)w2[wi - 20480];
    } else if (wi < 20480 + 16384 + 32768) {
      a3h[wi - 36864] = (_Float16)w3[wi - 36864];
    }
  }
}

// =====================================================================
// KNN phase 1: 8 shards/batch; per-thread FIFO + bitonic flush over 512 pts
// outputs per-shard sorted top-32 as sortable u64 keys (d-bits|idx)
// =====================================================================
#define LEXLT(d1,i1,d2,i2) ((d1) < (d2) || ((d1) == (d2) && (i1) < (i2)))

__global__ __launch_bounds__(64) void knn_p1(
    const float* __restrict__ newxyz, const float4* __restrict__ xyzpp, u64* __restrict__ keybuf)
{
#pragma clang fp contract(off)
  const int t = threadIdx.x;
  const int blk = blockIdx.x;
  const int b = blk >> 7, rem = blk & 127;
  const int shard = rem >> 4, qg = rem & 15;
  const int q = b*1024 + qg*64 + t;
  float qx = newxyz[(size_t)q*3+0], qy = newxyz[(size_t)q*3+1], qz = newxyz[(size_t)q*3+2];
  float qq = ((qx*qx) + (qy*qy)) + (qz*qz);

  const float INF = __builtin_inff();
  float td[32]; int ti[32];
  #pragma unroll
  for (int j = 0; j < 32; ++j) { td[j] = INF; ti[j] = 0x7FFFFFFF; }
  float root = INF;
  int cnt = 0;

  __shared__ float fdl[32][64];
  __shared__ int   fil[32][64];
  const float4* P = xyzpp + (size_t)b*HN + shard*512;

  auto flush = [&]() {
    float gd[32]; int gi2[32];
    #pragma unroll
    for (int j = 0; j < 32; ++j) {
      gd[j] = fdl[j][t]; gi2[j] = fil[j][t];
      if (j >= cnt) { gd[j] = INF; gi2[j] = 0x7FFFFFFF; }
    }
    cnt = 0;
    #pragma unroll
    for (int k = 2; k <= 32; k <<= 1) {
      #pragma unroll
      for (int j = k >> 1; j > 0; j >>= 1) {
        #pragma unroll
        for (int i = 0; i < 32; ++i) {
          int l = i ^ j;
          if (l > i) {
            bool up = ((i & k) == 0);
            bool sw = up ? LEXLT(gd[l], gi2[l], gd[i], gi2[i])
                         : LEXLT(gd[i], gi2[i], gd[l], gi2[l]);
            if (sw) { float tf = gd[i]; gd[i] = gd[l]; gd[l] = tf;
                      int   ii = gi2[i]; gi2[i] = gi2[l]; gi2[l] = ii; }
          }
        }
      }
    }
    #pragma unroll
    for (int i = 0; i < 32; ++i) {
      float od = gd[31-i]; int oi = gi2[31-i];
      if (LEXLT(od, oi, td[i], ti[i])) { td[i] = od; ti[i] = oi; }
    }
    #pragma unroll
    for (int j = 16; j > 0; j >>= 1) {
      #pragma unroll
      for (int i = 0; i < 32; ++i) {
        if ((i & j) == 0) {
          int l = i | j;
          if (LEXLT(td[l], ti[l], td[i], ti[i])) {
            float tf = td[i]; td[i] = td[l]; td[l] = tf;
            int   ii = ti[i]; ti[i] = ti[l]; ti[l] = ii;
          }
        }
      }
    }
    root = td[31];
  };

  for (int n0 = 0; n0 < 512; n0 += 8) {
    float4 pb[8];
    #pragma unroll
    for (int j = 0; j < 8; ++j) pb[j] = P[n0 + j];
    #pragma unroll
    for (int j = 0; j < 8; ++j) {
      float d = (qq + pb[j].w) - 2.0f*(((qx*pb[j].x) + (qy*pb[j].y)) + (qz*pb[j].z));
      if (d < root) { fdl[cnt][t] = d; fil[cnt][t] = shard*512 + n0 + j; cnt++; }
    }
    if (__ballot(cnt > 24)) flush();
  }
  if (__ballot(cnt > 0)) flush();

  // sortable u64 keys: (order-preserving f32 map << 32) | idx
  const size_t base = (size_t)(b*16 + qg) * 16384 + (size_t)shard * 2048;
  #pragma unroll
  for (int j = 0; j < 32; ++j) {
    unsigned bits = __float_as_uint(td[j]);
    unsigned s = bits ^ (((unsigned)((int)bits >> 31)) | 0x80000000u);
    keybuf[base + (size_t)j*64 + t] = ((u64)s << 32) | (unsigned)ti[j];
  }
}

// =====================================================================
// KNN phase 2: merge 8 shard-lists (8x32 keys) per query -> top-32 indices
// =====================================================================
__global__ __launch_bounds__(64) void knn_p2(const u64* __restrict__ keybuf, int* __restrict__ gidx)
{
  const int t = threadIdx.x;
  const int g = blockIdx.x;                 // (b*16 + qg)
  const size_t base = (size_t)g * 16384;

  u64 tk[32];
  #pragma unroll
  for (int j = 0; j < 32; ++j) tk[j] = ~0ULL;
  u64 root = ~0ULL;
  int cnt = 0;
  __shared__ u64 fk[32][64];

  auto flush64 = [&]() {
    u64 gd[32];
    #pragma unroll
    for (int j = 0; j < 32; ++j) {
      gd[j] = fk[j][t];
      if (j >= cnt) gd[j] = ~0ULL;
    }
    cnt = 0;
    #pragma unroll
    for (int k = 2; k <= 32; k <<= 1) {
      #pragma unroll
      for (int j = k >> 1; j > 0; j >>= 1) {
        #pragma unroll
        for (int i = 0; i < 32; ++i) {
          int l = i ^ j;
          if (l > i) {
            bool up = ((i & k) == 0);
            bool sw = up ? (gd[l] < gd[i]) : (gd[i] < gd[l]);
            if (sw) { u64 tf = gd[i]; gd[i] = gd[l]; gd[l] = tf; }
          }
        }
      }
    }
    #pragma unroll
    for (int i = 0; i < 32; ++i) {
      u64 od = gd[31-i];
      if (od < tk[i]) tk[i] = od;
    }
    #pragma unroll
    for (int j = 16; j > 0; j >>= 1) {
      #pragma unroll
      for (int i = 0; i < 32; ++i) {
        if ((i & j) == 0) {
          int l = i | j;
          if (tk[l] < tk[i]) { u64 tf = tk[i]; tk[i] = tk[l]; tk[l] = tf; }
        }
      }
    }
    root = tk[31];
  };

  for (int k0 = 0; k0 < 256; k0 += 8) {
    u64 kk[8];
    #pragma unroll
    for (int j = 0; j < 8; ++j) kk[j] = keybuf[base + (size_t)(k0 + j)*64 + t];
    #pragma unroll
    for (int j = 0; j < 8; ++j) {
      if (kk[j] < root) { fk[cnt][t] = kk[j]; cnt++; }
    }
    if (__ballot(cnt > 24)) flush64();
  }
  if (__ballot(cnt > 0)) flush64();

  const int q = g*64 + t;
  #pragma unroll
  for (int j = 0; j < 32; j += 4) {
    int4 v = { (int)(unsigned)tk[j], (int)(unsigned)tk[j+1], (int)(unsigned)tk[j+2], (int)(unsigned)tk[j+3] };
    *(int4*)(gidx + ((size_t)q << 5) + j) = v;
  }
}

// =====================================================================
// Fused conv+BN(+relu)+stats (+pool for MODE 3), fp16 MFMA 16x16x32
// =====================================================================
template<int MODE>
__global__ __launch_bounds__(256, 2) void conv_kernel(
    const _Float16* __restrict__ A, const _Float16* Bsrc,
    const int* __restrict__ gidx, const float4* __restrict__ xyzpp, const float* __restrict__ newxyz,
    const _Float16* __restrict__ bnA, const _Float16* __restrict__ bnB,
    _Float16* Yout, float* __restrict__ osum, float* __restrict__ osq,
    float* __restrict__ pool)
{
  const int tid = threadIdx.x;
  const int w = tid >> 6, l = tid & 63, ll = l & 15, lh = l >> 4;
  const int colbase = blockIdx.x * 256 + w * 64;
  const int b = colbase >> 15;
  const int AS = (MODE == 1) ? 160 : 128;
  const _Float16* Ap = A + (MODE == 3 ? (size_t)blockIdx.y * 128 * 128 : 0);

  f32x4 acc[8][4] = {};

  half8 bnAv[4], bnBv[4];
  if constexpr (MODE >= 2) {
    #pragma unroll
    for (int c = 0; c < 4; ++c) {
      int k0 = c*32 + lh*8;
      bnAv[c] = *(const half8*)(bnA + k0);
      bnBv[c] = *(const half8*)(bnB + k0);
    }
  }
  int gidxv[4];
  if constexpr (MODE == 1) {
    #pragma unroll
    for (int nf = 0; nf < 4; ++nf) gidxv[nf] = gidx[colbase + nf*16 + ll];
  }

  const int NCH = (MODE == 1) ? 5 : 4;
  #pragma unroll
  for (int c = 0; c < NCH; ++c) {
    half8 a[8];
    #pragma unroll
    for (int mf = 0; mf < 8; ++mf)
      a[mf] = *(const half8*)(Ap + (size_t)(mf*16 + ll)*AS + c*32 + lh*8);
    half8 bfr[4];
    #pragma unroll
    for (int nf = 0; nf < 4; ++nf) {
      if constexpr (MODE == 1) {
        if (c < 4) {
          bfr[nf] = *(const half8*)(Bsrc + ((size_t)(b*HN + gidxv[nf]))*HC + c*32 + lh*8);
        } else {
          half8 z = {};
          if (lh == 0) {
            float4 pw = xyzpp[b*HN + gidxv[nf]];
            int col = colbase + nf*16 + ll;
            int s = (col >> 5) & (HS-1);
            const float* nx = newxyz + (size_t)(b*HS + s)*3;
            z[0] = (_Float16)(pw.x - nx[0]);
            z[1] = (_Float16)(pw.y - nx[1]);
            z[2] = (_Float16)(pw.z - nx[2]);
          }
          bfr[nf] = z;
        }
      } else {
        half8 v = *(const half8*)(Bsrc + ((size_t)(colbase + nf*16 + ll))*HC + c*32 + lh*8);
        v = v * bnAv[c] + bnBv[c];
        half8 hz = {};
        bfr[nf] = __builtin_elementwise_max(v, hz);
      }
    }
    #pragma unroll
    for (int mf = 0; mf < 8; ++mf)
      #pragma unroll
      for (int nf = 0; nf < 4; ++nf)
        acc[mf][nf] = __builtin_amdgcn_mfma_f32_16x16x32_f16(a[mf], bfr[nf], acc[mf][nf], 0, 0, 0);
  }

  // ---------------- epilogue ----------------
  __shared__ float bsum[128], bsq[128];
  if (tid < 128) { bsum[tid] = 0.0f; bsq[tid] = 0.0f; }
  __syncthreads();

  #pragma unroll
  for (int mf = 0; mf < 8; ++mf) {
    int ch0 = mf*16 + lh*4;
    if constexpr (MODE != 3) {
      #pragma unroll
      for (int nf = 0; nf < 4; ++nf) {
        int col = colbase + nf*16 + ll;
        half4v hv;
        #pragma unroll
        for (int r = 0; r < 4; ++r) hv[r] = (_Float16)acc[mf][nf][r];
        *(half4v*)(Yout + (size_t)col*HC + ch0) = hv;
      }
    } else {
      #pragma unroll
      for (int g = 0; g < 2; ++g) {
        float mx[4];
        #pragma unroll
        for (int r = 0; r < 4; ++r) mx[r] = fmaxf(acc[mf][2*g][r], acc[mf][2*g+1][r]);
        #pragma unroll
        for (int m = 1; m <= 8; m <<= 1)
          #pragma unroll
          for (int r = 0; r < 4; ++r) mx[r] = fmaxf(mx[r], __shfl_xor(mx[r], m, 64));
        if (ll == 0) {
          int s = ((colbase + g*32) >> 5) & (HS-1);
          int chg = blockIdx.y*128 + ch0;
          #pragma unroll
          for (int r = 0; r < 4; ++r)
            pool[(((size_t)(b*256 + chg + r)) << 10) + s] = mx[r];
        }
      }
    }
    float sv[4] = {0,0,0,0}, qv[4] = {0,0,0,0};
    #pragma unroll
    for (int nf = 0; nf < 4; ++nf)
      #pragma unroll
      for (int r = 0; r < 4; ++r) { float v = acc[mf][nf][r]; sv[r] += v; qv[r] += v*v; }
    #pragma unroll
    for (int m = 1; m <= 8; m <<= 1)
      #pragma unroll
      for (int r = 0; r < 4; ++r) { sv[r] += __shfl_xor(sv[r], m, 64); qv[r] += __shfl_xor(qv[r], m, 64); }
    if (ll == 0) {
      #pragma unroll
      for (int r = 0; r < 4; ++r) { atomicAdd(&bsum[ch0+r], sv[r]); atomicAdd(&bsq[ch0+r], qv[r]); }
    }
  }
  __syncthreads();
  if (tid < 128) {
    int choff = (MODE == 3) ? blockIdx.y*128 : 0;
    atomicAdd(&osum[choff + tid], bsum[tid]);
    atomicAdd(&osq[choff + tid], bsq[tid]);
  }
}

// =====================================================================
__global__ void fin_kernel(const float* __restrict__ sum, const float* __restrict__ sq,
                           const float* __restrict__ g, const float* __restrict__ be,
                           _Float16* __restrict__ Ah, _Float16* __restrict__ Bh,
                           float* __restrict__ Af, float* __restrict__ Bf, int C)
{
  int c = threadIdx.x;
  if (c < C) {
    float mean = sum[c] * (1.0f/524288.0f);
    float var  = sq[c]  * (1.0f/524288.0f) - mean*mean;
    float a  = g[c] * rsqrtf(var + 1e-5f);
    float bb = be[c] - mean*a;
    if (Ah) { Ah[c] = (_Float16)a; Bh[c] = (_Float16)bb; }
    else    { Af[c] = a; Bf[c] = bb; }
  }
}

// =====================================================================
__global__ __launch_bounds__(256) void final_affine(float* __restrict__ outp,
                                                    const float* __restrict__ Af,
                                                    const float* __restrict__ Bf)
{
  int i = blockIdx.x*256 + threadIdx.x;
  float4 v = ((float4*)outp)[i];
  int ch = ((i << 2) >> 10) & 255;
  float a = Af[ch], bb = Bf[ch];
  v.x = fmaxf(v.x*a + bb, 0.0f);
  v.y = fmaxf(v.y*a + bb, 0.0f);
  v.z = fmaxf(v.z*a + bb, 0.0f);
  v.w = fmaxf(v.w*a + bb, 0.0f);
  ((float4*)outp)[i] = v;
}

// =====================================================================
extern "C" void kernel_launch(void* const* d_in, const int* in_sizes, int n_in,
                              void* d_out, int out_size, void* d_ws, size_t ws_size,
                              hipStream_t stream) {
  const float* xyz      = (const float*)d_in[0];
  const float* features = (const float*)d_in[1];
  const float* w1  = (const float*)d_in[2];
  const float* g1  = (const float*)d_in[3];
  const float* b1v = (const float*)d_in[4];
  const float* w2  = (const float*)d_in[5];
  const float* g2  = (const float*)d_in[6];
  const float* b2v = (const float*)d_in[7];
  const float* w3  = (const float*)d_in[8];
  const float* g3  = (const float*)d_in[9];
  const float* b3v = (const float*)d_in[10];
  float* out = (float*)d_out;
  char* ws = (char*)d_ws;

  float* stats = (float*)(ws + WS_STATS);
  float* sum1 = stats;       float* sq1 = stats + 128;
  float* sum2 = stats + 256; float* sq2 = stats + 384;
  float* sum3 = stats + 512; float* sq3 = stats + 768;
  _Float16* A1h = (_Float16*)(ws + WS_BN);
  _Float16* B1h = A1h + 128;
  _Float16* A2h = A1h + 256;
  _Float16* B2h = A1h + 384;
  float* a3f = (float*)(ws + WS_BN + 1024);
  float* b3f = a3f + 256;
  _Float16* a1h = (_Float16*)(ws + WS_A1H);
  _Float16* a2h = (_Float16*)(ws + WS_A2H);
  _Float16* a3h = (_Float16*)(ws + WS_A3H);
  float4* xyzpp = (float4*)(ws + WS_XYZPP);
  int* gidx = (int*)(ws + WS_GIDX);
  _Float16* featt = (_Float16*)(ws + WS_FEATT);
  u64* keybuf = (u64*)(ws + WS_Y1);       // y1 region reused before conv1
  _Float16* y1 = (_Float16*)(ws + WS_Y1);
  _Float16* y2 = y1;   // conv2 output overwrites y1 in place (per-column independence)

  hipMemsetAsync(ws + WS_STATS, 0, 4096, stream);

  head_kernel<<<1568, 256, 0, stream>>>(xyz, features, w1, w2, w3,
                                        a1h, a2h, a3h, featt, xyzpp, out);
  knn_p1<<<2048, 64, 0, stream>>>(out, xyzpp, keybuf);
  knn_p2<<<256, 64, 0, stream>>>(keybuf, gidx);

  conv_kernel<1><<<2048, 256, 0, stream>>>(a1h, featt, gidx, xyzpp, out,
                                           nullptr, nullptr, y1, sum1, sq1, nullptr);
  fin_kernel<<<1, 256, 0, stream>>>(sum1, sq1, g1, b1v, A1h, B1h, nullptr, nullptr, 128);

  conv_kernel<2><<<2048, 256, 0, stream>>>(a2h, y1, nullptr, nullptr, nullptr,
                                           A1h, B1h, y2, sum2, sq2, nullptr);
  fin_kernel<<<1, 256, 0, stream>>>(sum2, sq2, g2, b2v, A2h, B2h, nullptr, nullptr, 128);

  conv_kernel<3><<<dim3(2048, 2), 256, 0, stream>>>(a3h, y2, nullptr, nullptr, nullptr,
                                                    A2h, B2h, nullptr, sum3, sq3, out + 49152);
  fin_kernel<<<1, 256, 0, stream>>>(sum3, sq3, g3, b3v, nullptr, nullptr, a3f, b3f, 256);

  final_affine<<<4096, 256, 0, stream>>>(out + 49152, a3f, b3f);
}